// Round 12
// baseline (121.146 us; speedup 1.0000x reference)
//
#include <hip/hip_runtime.h>

#define F_ALPHA 0.25f
#define F_EPS   1e-8f
#define NB 4     // preds per block
#define REPS 5   // DIAGNOSTIC: repeat main phase to surface kernel in rocprof top-5

// R5 structure (best: 32.9us). Phase 2 repeated REPS times with a rep-rotated
// target assignment (tt = (t+rep) mod T): every (n,t) cost is recomputed and
// re-stored with identical values each rep -> idempotent, deterministic, but
// not hoistable by LICM. Counters for the long dispatch reflect the real body.
__global__ void __launch_bounds__(256)
fused_cost_kernel(const float* __restrict__ logits,      // [N, C]
                  const float4* __restrict__ pred_boxes, // [N]
                  const float4* __restrict__ tgt_boxes,  // [T]
                  const int* __restrict__ tgt_ids,       // [T]
                  float* __restrict__ out,               // [N, T]
                  int N, int C, int T, int reps) {
    __shared__ float fcls[NB][96];                       // C <= 96
    const int n0  = blockIdx.x * NB;
    const int tid = threadIdx.x;

    // ---- phase 1: one wave per pred row ----
    {
        const int w = tid >> 6, l = tid & 63;
        const float* lrow = logits + (size_t)(n0 + w) * C;
        for (int c = l; c < C; c += 64) {
            float x = lrow[c];
            float p = 1.0f / (1.0f + expf(-x));
            float om = 1.0f - p;
            float pos = F_ALPHA * om * om * (-logf(p + F_EPS));
            float neg = (1.0f - F_ALPHA) * p * p * (-logf(om + F_EPS));
            fcls[w][c] = 2.0f * (pos - neg) + 2.0f;      // prescaled 2*cls+2
        }
    }

    // pred-side params (block-uniform) + output row pointers
    float pcx[NB], pcy[NB], pw_[NB], ph_[NB];
    float px1[NB], py1[NB], px2[NB], py2[NB], parea[NB];
    float* op[NB];
#pragma unroll
    for (int i = 0; i < NB; ++i) {
        const int n = n0 + i;                            // N % NB == 0
        float4 pb = pred_boxes[n];
        pcx[i] = pb.x; pcy[i] = pb.y; pw_[i] = pb.z; ph_[i] = pb.w;
        px1[i] = pb.x - 0.5f * pb.z;  py1[i] = pb.y - 0.5f * pb.w;
        px2[i] = pb.x + 0.5f * pb.z;  py2[i] = pb.y + 0.5f * pb.w;
        parea[i] = pb.z * pb.w;
        op[i] = out + (size_t)n * T;
    }
    __syncthreads();

    auto body = [&](int t) {
        float4 tb = tgt_boxes[t];
        int id = tgt_ids[t];
        float clsv[NB] = {fcls[0][id], fcls[1][id], fcls[2][id], fcls[3][id]};
        float tx1 = tb.x - 0.5f * tb.z, ty1 = tb.y - 0.5f * tb.w;
        float tx2 = tb.x + 0.5f * tb.z, ty2 = tb.y + 0.5f * tb.w;
        float tarea = tb.z * tb.w;
#pragma unroll
        for (int i = 0; i < NB; ++i) {
            float l1 = (fabsf(pcx[i] - tb.x) + fabsf(pcy[i] - tb.y))
                     + (fabsf(pw_[i] - tb.z) + fabsf(ph_[i] - tb.w));

            float ix1 = fmaxf(px1[i], tx1), iy1 = fmaxf(py1[i], ty1);
            float ix2 = fminf(px2[i], tx2), iy2 = fminf(py2[i], ty2);
            float iw = fmaxf(ix2 - ix1, 0.0f), ih = fmaxf(iy2 - iy1, 0.0f);
            float inter = iw * ih;
            float uni = parea[i] + tarea - inter;

            float ex1 = fminf(px1[i], tx1), ey1 = fminf(py1[i], ty1);
            float ex2 = fmaxf(px2[i], tx2), ey2 = fmaxf(py2[i], ty2);
            float earea = (ex2 - ex1) * (ey2 - ey1);     // wh >= 0 for [0,1) boxes

            float v = fmaf(5.0f, l1, clsv[i]);           // 5*l1 + 2*cls + 2
            v = fmaf(-2.0f, inter * __builtin_amdgcn_rcpf(uni), v);
            v = fmaf(-2.0f, uni * __builtin_amdgcn_rcpf(earea), v);
            op[i][t] = v;
        }
    };

    // ---- phase 2: REPS sweeps, rep-rotated (identical output each rep) ----
    for (int rep = 0; rep < reps; ++rep) {
        for (int t = tid; t < T; t += 256) {
            int tt = t + rep;
            if (tt >= T) tt -= T;
            body(tt);
        }
    }
}

extern "C" void kernel_launch(void* const* d_in, const int* in_sizes, int n_in,
                              void* d_out, int out_size, void* d_ws, size_t ws_size,
                              hipStream_t stream) {
    const float* logits = (const float*)d_in[0];   // [bs, Q, C]
    const float* pboxes = (const float*)d_in[1];   // [bs, Q, 4]
    const float* tboxes = (const float*)d_in[2];   // [T, 4]
    const int*   tids   = (const int*)d_in[3];     // [T]

    int N = in_sizes[1] / 4;          // bs*Q = 14400
    int C = in_sizes[0] / N;          // 91
    int T = in_sizes[2] / 4;          // 1600

    int grid = N / NB;                // 3600
    fused_cost_kernel<<<grid, 256, 0, stream>>>(
        logits, (const float4*)pboxes, (const float4*)tboxes, tids,
        (float*)d_out, N, C, T, REPS);
}

// Round 13
// 32.197 us; speedup vs baseline: 3.7627x; 3.7627x over previous
//
#include <hip/hip_runtime.h>

#define F_ALPHA 0.25f
#define F_EPS   1e-8f
#define NB 4   // preds per block

// R5 skeleton, VALU-lean body (R12 diagnostic: VALU-issue-bound, 345 instr/body).
// Cuts: enclosing box via identity ew = pw + tw - dx (no extra min/max),
// fma conversions, hoisted area-sum, single b128 class gather.
__global__ void __launch_bounds__(256)
fused_cost_kernel(const float* __restrict__ logits,      // [N, C]
                  const float4* __restrict__ pred_boxes, // [N]
                  const float4* __restrict__ tgt_boxes,  // [T]
                  const int* __restrict__ tgt_ids,       // [T]
                  float* __restrict__ out,               // [N, T]
                  int N, int C, int T) {
    __shared__ float4 fclsT[96];                         // [class] -> NB costs
    const int n0  = blockIdx.x * NB;
    const int tid = threadIdx.x;

    // ---- phase 1: wave w computes pred (n0+w)'s focal row, transposed ----
    {
        const int w = tid >> 6, l = tid & 63;
        const float* lrow = logits + (size_t)(n0 + w) * C;
        for (int c = l; c < C; c += 64) {
            float x = lrow[c];
            float p = 1.0f / (1.0f + expf(-x));
            float om = 1.0f - p;
            float pos = F_ALPHA * om * om * (-logf(p + F_EPS));
            float neg = (1.0f - F_ALPHA) * p * p * (-logf(om + F_EPS));
            ((float*)fclsT)[c * NB + w] = 2.0f * (pos - neg) + 2.0f; // 2*cls+2
        }
    }

    // pred-side params (block-uniform)
    float pcx[NB], pcy[NB], pw_[NB], ph_[NB];
    float px1[NB], py1[NB], px2[NB], py2[NB], parea[NB];
    float* op[NB];
#pragma unroll
    for (int i = 0; i < NB; ++i) {
        const int n = n0 + i;                            // N % NB == 0
        float4 pb = pred_boxes[n];
        pcx[i] = pb.x; pcy[i] = pb.y; pw_[i] = pb.z; ph_[i] = pb.w;
        px1[i] = fmaf(-0.5f, pb.z, pb.x);  py1[i] = fmaf(-0.5f, pb.w, pb.y);
        px2[i] = fmaf( 0.5f, pb.z, pb.x);  py2[i] = fmaf( 0.5f, pb.w, pb.y);
        parea[i] = pb.z * pb.w;
        op[i] = out + (size_t)n * T;
    }
    __syncthreads();

    auto body = [&](int t) {
        float4 tb = tgt_boxes[t];                        // unit-stride float4
        int id = tgt_ids[t];                             // unit-stride dword
        float4 cls4 = fclsT[id];                         // one ds_read_b128
        const float clsv[NB] = {cls4.x, cls4.y, cls4.z, cls4.w};

        float tx1 = fmaf(-0.5f, tb.z, tb.x), ty1 = fmaf(-0.5f, tb.w, tb.y);
        float tx2 = fmaf( 0.5f, tb.z, tb.x), ty2 = fmaf( 0.5f, tb.w, tb.y);
        float tarea = tb.z * tb.w;

#pragma unroll
        for (int i = 0; i < NB; ++i) {
            // intersection extents (dx,dy signed; clamp only for inter)
            float ax = fmaxf(px1[i], tx1), bx = fminf(px2[i], tx2);
            float ay = fmaxf(py1[i], ty1), by = fminf(py2[i], ty2);
            float dx = bx - ax, dy = by - ay;
            float iw = fmaxf(dx, 0.0f), ih = fmaxf(dy, 0.0f);
            float inter = iw * ih;
            float uni = (parea[i] + tarea) - inter;

            // enclosing box via identity: ex2-ex1 == pw + tw - dx (exact)
            float ew = (pw_[i] + tb.z) - dx;
            float eh = (ph_[i] + tb.w) - dy;
            float earea = ew * eh;

            float l1 = (fabsf(pcx[i] - tb.x) + fabsf(pcy[i] - tb.y))
                     + (fabsf(pw_[i] - tb.z) + fabsf(ph_[i] - tb.w));

            float v = fmaf(5.0f, l1, clsv[i]);           // 5*l1 + 2*cls + 2
            v = fmaf(-2.0f, inter * __builtin_amdgcn_rcpf(uni), v);
            v = fmaf(-2.0f, uni * __builtin_amdgcn_rcpf(earea), v);
            op[i][t] = v;                                // coalesced dword store
        }
    };

    // ---- phase 2: unrolled-by-2 target sweep ----
    int t = tid;
    for (; t + 256 < T; t += 512) { body(t); body(t + 256); }
    for (; t < T; t += 256) body(t);
}

extern "C" void kernel_launch(void* const* d_in, const int* in_sizes, int n_in,
                              void* d_out, int out_size, void* d_ws, size_t ws_size,
                              hipStream_t stream) {
    const float* logits = (const float*)d_in[0];   // [bs, Q, C]
    const float* pboxes = (const float*)d_in[1];   // [bs, Q, 4]
    const float* tboxes = (const float*)d_in[2];   // [T, 4]
    const int*   tids   = (const int*)d_in[3];     // [T]

    int N = in_sizes[1] / 4;          // bs*Q = 14400
    int C = in_sizes[0] / N;          // 91
    int T = in_sizes[2] / 4;          // 1600

    int grid = N / NB;                // 3600
    fused_cost_kernel<<<grid, 256, 0, stream>>>(
        logits, (const float4*)pboxes, (const float4*)tboxes, tids,
        (float*)d_out, N, C, T);
}

// Round 14
// 31.644 us; speedup vs baseline: 3.8284x; 1.0175x over previous
//
#include <hip/hip_runtime.h>

#define F_ALPHA 0.25f
#define F_EPS   1e-8f
#define NB 4   // preds per block

// R13 skeleton + (256,4) launch bounds: R12 showed VGPR_Count=32 — the
// occupancy-greedy allocator was rematerializing ~40 pred-state values per
// body (the missing ~200 instrs/body). 128-VGPR budget lets pred state live
// in registers across the whole sweep. Also: single-rcp GIoU form.
__global__ void __launch_bounds__(256, 4)
fused_cost_kernel(const float* __restrict__ logits,      // [N, C]
                  const float4* __restrict__ pred_boxes, // [N]
                  const float4* __restrict__ tgt_boxes,  // [T]
                  const int* __restrict__ tgt_ids,       // [T]
                  float* __restrict__ out,               // [N, T]
                  int N, int C, int T) {
    __shared__ float4 fclsT[96];                         // [class] -> NB costs
    const int n0  = blockIdx.x * NB;
    const int tid = threadIdx.x;

    // ---- phase 1: wave w computes pred (n0+w)'s focal row, transposed ----
    {
        const int w = tid >> 6, l = tid & 63;
        const float* lrow = logits + (size_t)(n0 + w) * C;
        for (int c = l; c < C; c += 64) {
            float x = lrow[c];
            float p = 1.0f / (1.0f + expf(-x));
            float om = 1.0f - p;
            float pos = F_ALPHA * om * om * (-logf(p + F_EPS));
            float neg = (1.0f - F_ALPHA) * p * p * (-logf(om + F_EPS));
            ((float*)fclsT)[c * NB + w] = 2.0f * (pos - neg) + 2.0f; // 2*cls+2
        }
    }

    // pred-side params (block-uniform; should now STAY in VGPRs)
    float pcx[NB], pcy[NB], pw_[NB], ph_[NB];
    float px1[NB], py1[NB], px2[NB], py2[NB], parea[NB];
    float* op[NB];
#pragma unroll
    for (int i = 0; i < NB; ++i) {
        const int n = n0 + i;                            // N % NB == 0
        float4 pb = pred_boxes[n];
        pcx[i] = pb.x; pcy[i] = pb.y; pw_[i] = pb.z; ph_[i] = pb.w;
        px1[i] = fmaf(-0.5f, pb.z, pb.x);  py1[i] = fmaf(-0.5f, pb.w, pb.y);
        px2[i] = fmaf( 0.5f, pb.z, pb.x);  py2[i] = fmaf( 0.5f, pb.w, pb.y);
        parea[i] = pb.z * pb.w;
        op[i] = out + (size_t)n * T;
    }
    __syncthreads();

    auto body = [&](int t) {
        float4 tb = tgt_boxes[t];                        // unit-stride float4
        int id = tgt_ids[t];                             // unit-stride dword
        float4 cls4 = fclsT[id];                         // one ds_read_b128
        const float clsv[NB] = {cls4.x, cls4.y, cls4.z, cls4.w};

        float tx1 = fmaf(-0.5f, tb.z, tb.x), ty1 = fmaf(-0.5f, tb.w, tb.y);
        float tx2 = fmaf( 0.5f, tb.z, tb.x), ty2 = fmaf( 0.5f, tb.w, tb.y);
        float tarea = tb.z * tb.w;

#pragma unroll
        for (int i = 0; i < NB; ++i) {
            float ax = fmaxf(px1[i], tx1), bx = fminf(px2[i], tx2);
            float ay = fmaxf(py1[i], ty1), by = fminf(py2[i], ty2);
            float dx = bx - ax, dy = by - ay;
            float iw = fmaxf(dx, 0.0f), ih = fmaxf(dy, 0.0f);
            float inter = iw * ih;
            float uni = (parea[i] + tarea) - inter;

            float ew = (pw_[i] + tb.z) - dx;             // enclosing identity
            float eh = (ph_[i] + tb.w) - dy;
            float earea = ew * eh;

            float l1 = (fabsf(pcx[i] - tb.x) + fabsf(pcy[i] - tb.y))
                     + (fabsf(pw_[i] - tb.z) + fabsf(ph_[i] - tb.w));

            // 2*inter/uni + 2*uni/earea = 2*(inter*earea + uni^2)*rcp(uni*earea)
            float den = uni * earea;
            float r   = __builtin_amdgcn_rcpf(den);
            float num = fmaf(uni, uni, inter * earea);

            float v = fmaf(5.0f, l1, clsv[i]);           // 5*l1 + 2*cls + 2
            v = fmaf(-2.0f, num * r, v);
            op[i][t] = v;                                // coalesced dword store
        }
    };

    // ---- phase 2: unrolled-by-2 target sweep ----
    int t = tid;
    for (; t + 256 < T; t += 512) { body(t); body(t + 256); }
    for (; t < T; t += 256) body(t);
}

extern "C" void kernel_launch(void* const* d_in, const int* in_sizes, int n_in,
                              void* d_out, int out_size, void* d_ws, size_t ws_size,
                              hipStream_t stream) {
    const float* logits = (const float*)d_in[0];   // [bs, Q, C]
    const float* pboxes = (const float*)d_in[1];   // [bs, Q, 4]
    const float* tboxes = (const float*)d_in[2];   // [T, 4]
    const int*   tids   = (const int*)d_in[3];     // [T]

    int N = in_sizes[1] / 4;          // bs*Q = 14400
    int C = in_sizes[0] / N;          // 91
    int T = in_sizes[2] / 4;          // 1600

    int grid = N / NB;                // 3600
    fused_cost_kernel<<<grid, 256, 0, stream>>>(
        logits, (const float4*)pboxes, (const float4*)tboxes, tids,
        (float*)d_out, N, C, T);
}